// Round 2
// baseline (531.241 us; speedup 1.0000x reference)
//
#include <hip/hip_runtime.h>

#define B_   8
#define S_   2048
#define IN_  96
#define H_   256

typedef float f32x4 __attribute__((ext_vector_type(4)));
typedef short bf16x8 __attribute__((ext_vector_type(8)));   // 8 bf16 in 4 VGPRs

__device__ __forceinline__ unsigned short f2bf(float x) {
    unsigned int u = __float_as_uint(x);
    u += 0x7fffu + ((u >> 16) & 1u);          // round-nearest-even
    return (unsigned short)(u >> 16);
}

// ---------------------------------------------------------------------------
// Kernel 0: convert W[96][256] fp32 -> wt[256][96] bf16 (transposed), x3 proj.
// grid = 24 blocks (3 proj x 8 h-chunks of 32), 256 threads.
// ---------------------------------------------------------------------------
__global__ __launch_bounds__(256) void wconv_kernel(
    const float* __restrict__ Wq, const float* __restrict__ Wk,
    const float* __restrict__ Wv, unsigned short* __restrict__ wt)
{
    const int p  = blockIdx.x >> 3;
    const int h0 = (blockIdx.x & 7) * 32;
    const float* W = (p == 0) ? Wq : (p == 1) ? Wk : Wv;
    unsigned short* dst = wt + (size_t)p * H_ * IN_ + (size_t)h0 * IN_;

    __shared__ unsigned short lds[32][100];   // [h_local][f], padded
    const int t = threadIdx.x;
    #pragma unroll
    for (int i = 0; i < 12; ++i) {            // 3072 elements of this chunk
        int idx = i * 256 + t;
        int f = idx >> 5;                     // 0..95
        int hl = idx & 31;
        lds[hl][f] = f2bf(W[f * H_ + h0 + hl]);
    }
    __syncthreads();
    #pragma unroll
    for (int j = 0; j < 6; ++j) {             // 1536 u32 = 3072 ushort, coalesced
        int e = (j * 256 + t) * 2;            // local element index (even)
        int hl = e / IN_, f = e % IN_;
        unsigned int pk = (unsigned int)lds[hl][f] |
                          ((unsigned int)lds[hl][f + 1] << 16);
        ((unsigned int*)dst)[j * 256 + t] = pk;
    }
}

// ---------------------------------------------------------------------------
// Kernel 1: QKV projection via MFMA.  out^T[h][r] = sum_f wt[h][f] * X[r][f].
// One wave per 16-row strip; A = wt rows (contiguous bf16x8), B = X rows
// (fp32 -> bf16 on the fly). C layout: lane(col,quad) holds
// out[r=col][h = ht*16 + quad*4 + reg].
//   qp[b][s][h], kp[b][s][h] bf16 row-major; vt[b][h][s] bf16 transposed.
// ---------------------------------------------------------------------------
__global__ __launch_bounds__(64) void proj_mfma_kernel(
    const float* __restrict__ query, const float* __restrict__ key,
    const float* __restrict__ value, const unsigned short* __restrict__ wt,
    const float* __restrict__ bq, const float* __restrict__ bk,
    const float* __restrict__ bv,
    unsigned short* __restrict__ qp, unsigned short* __restrict__ kp,
    unsigned short* __restrict__ vt)
{
    const int lane = threadIdx.x;
    const int col  = lane & 15;
    const int quad = lane >> 4;
    const int strip = blockIdx.x;             // 0..1023, 16 rows each
    const int b  = strip >> 7;
    const int s0 = (strip & 127) << 4;

    const float* srcs[3]  = { query, key, value };
    const float* biases[3] = { bq, bk, bv };

    #pragma unroll
    for (int p = 0; p < 3; ++p) {
        // B-fragments: X[r=col][k], k = kc*32 + quad*8 + j
        const float* Xrow = srcs[p] + (size_t)(strip * 16 + col) * IN_ + quad * 8;
        bf16x8 xf[3];
        #pragma unroll
        for (int kc = 0; kc < 3; ++kc) {
            f32x4 lo = *(const f32x4*)(Xrow + kc * 32);
            f32x4 hi = *(const f32x4*)(Xrow + kc * 32 + 4);
            bf16x8 v;
            #pragma unroll
            for (int j = 0; j < 4; ++j) v[j]     = (short)f2bf(lo[j]);
            #pragma unroll
            for (int j = 0; j < 4; ++j) v[4 + j] = (short)f2bf(hi[j]);
            xf[kc] = v;
        }
        const unsigned short* wbase = wt + (size_t)p * H_ * IN_;
        const float* bias = biases[p];

        #pragma unroll
        for (int ht = 0; ht < 16; ++ht) {
            f32x4 acc = (f32x4)(0.0f);
            #pragma unroll
            for (int kc = 0; kc < 3; ++kc) {
                bf16x8 wf = *(const bf16x8*)(wbase + (size_t)(ht * 16 + col) * IN_
                                             + kc * 32 + quad * 8);
                acc = __builtin_amdgcn_mfma_f32_16x16x32_bf16(wf, xf[kc], acc, 0, 0, 0);
            }
            f32x4 b4 = *(const f32x4*)(bias + ht * 16 + quad * 4);
            acc += b4;
            if (p < 2) {
                unsigned short* dstp = (p == 0) ? qp : kp;
                unsigned long long pk = 0;
                #pragma unroll
                for (int r = 0; r < 4; ++r)
                    pk |= (unsigned long long)f2bf(acc[r]) << (16 * r);
                *(unsigned long long*)&dstp[(size_t)(strip * 16 + col) * H_
                                            + ht * 16 + quad * 4] = pk;
            } else {
                #pragma unroll
                for (int r = 0; r < 4; ++r)
                    vt[(size_t)b * H_ * S_ + (size_t)(ht * 16 + quad * 4 + r) * S_
                       + s0 + col] = f2bf(acc[r]);
            }
        }
    }
}

// ---------------------------------------------------------------------------
// Kernel 2: flash attention (online softmax) + LayerNorm, fused.
// Block = 256 thr = 4 waves, one 16-row Q strip; waves split keys 4-way
// (64-key tiles, stride 256) and merge through a shared fp32 LDS accumulator.
// S^T = mfma(K_frag, Q_frag) so softmax stats are per-lane (q = lane&15).
// ---------------------------------------------------------------------------
__global__ __launch_bounds__(256, 4) void attn_kernel(
    const unsigned short* __restrict__ qp, const unsigned short* __restrict__ kp,
    const unsigned short* __restrict__ vt, const int* __restrict__ mask,
    const float* __restrict__ gamma, const float* __restrict__ beta,
    float* __restrict__ out)
{
    __shared__ unsigned short P_lds[4][16][72];   // per-wave P transpose buffer
    __shared__ float mbuf[4][16], lbuf[4][16];
    __shared__ float Obuf[16][260];               // fp32 merge accumulator (pad 260)

    const int tid  = threadIdx.x;
    const int wave = tid >> 6;
    const int lane = tid & 63;
    const int col  = lane & 15;                   // q index within strip
    const int quad = lane >> 4;

    const int strip = blockIdx.x;                 // 0..1023
    const int b  = strip >> 7;
    const int q0 = (strip & 127) << 4;

    // Q B-fragments, kept in registers for the whole kernel.
    const unsigned short* qbase = qp + (size_t)(b * S_ + q0 + col) * H_ + quad * 8;
    bf16x8 qf[8];
    #pragma unroll
    for (int s = 0; s < 8; ++s) qf[s] = *(const bf16x8*)(qbase + s * 32);

    f32x4 O[16];
    #pragma unroll
    for (int ht = 0; ht < 16; ++ht) O[ht] = (f32x4)(0.0f);
    float m = -1e30f, l = 0.0f;

    const unsigned short* kbase = kp + (size_t)(b * S_ + col) * H_ + quad * 8;
    const unsigned short* vbase = vt + (size_t)(b * H_ + col) * S_ + quad * 8;
    const int* mbase = mask + (size_t)(b * S_ + q0 + col) * S_ + quad * 4;
    unsigned short* Prow = &P_lds[wave][col][0];

    for (int kb = wave * 64; kb < S_; kb += 256) {
        int4 msk[4];
        #pragma unroll
        for (int mt = 0; mt < 4; ++mt)
            msk[mt] = *(const int4*)(mbase + kb + mt * 16);

        // ---- S^T = K · Q^T  (row = key, col = q) ----
        f32x4 St[4];
        #pragma unroll
        for (int mt = 0; mt < 4; ++mt) St[mt] = (f32x4)(0.0f);
        #pragma unroll
        for (int s = 0; s < 8; ++s) {
            #pragma unroll
            for (int mt = 0; mt < 4; ++mt) {
                bf16x8 kf = *(const bf16x8*)(kbase + (size_t)(kb + mt * 16) * H_ + s * 32);
                St[mt] = __builtin_amdgcn_mfma_f32_16x16x32_bf16(kf, qf[s], St[mt], 0, 0, 0);
            }
        }

        // ---- scale + mask + online softmax (stats per lane, q = col) ----
        float sc[4][4];
        float mloc = -1e30f;
        #pragma unroll
        for (int mt = 0; mt < 4; ++mt) {
            int mv[4] = { msk[mt].x, msk[mt].y, msk[mt].z, msk[mt].w };
            #pragma unroll
            for (int r = 0; r < 4; ++r) {
                float x = St[mt][r] * 0.0625f;          // / sqrt(256)
                x = (mv[r] == 0) ? -1e10f : x;
                sc[mt][r] = x;
                mloc = fmaxf(mloc, x);
            }
        }
        mloc = fmaxf(mloc, __shfl_xor(mloc, 16));
        mloc = fmaxf(mloc, __shfl_xor(mloc, 32));
        float mnew  = fmaxf(m, mloc);
        float alpha = __expf(m - mnew);
        float ps = 0.0f;
        #pragma unroll
        for (int mt = 0; mt < 4; ++mt) {
            unsigned long long pk64 = 0;
            #pragma unroll
            for (int r = 0; r < 4; ++r) {
                float p = __expf(sc[mt][r] - mnew);
                ps += p;
                pk64 |= (unsigned long long)f2bf(p) << (16 * r);
            }
            *(unsigned long long*)&Prow[mt * 16 + quad * 4] = pk64;
        }
        ps += __shfl_xor(ps, 16);
        ps += __shfl_xor(ps, 32);
        l = l * alpha + ps;
        m = mnew;

        float a4[4];
        #pragma unroll
        for (int r = 0; r < 4; ++r) a4[r] = __shfl(alpha, quad * 4 + r);
        #pragma unroll
        for (int ht = 0; ht < 16; ++ht) {
            O[ht][0] *= a4[0]; O[ht][1] *= a4[1];
            O[ht][2] *= a4[2]; O[ht][3] *= a4[3];
        }

        // ---- O += P · V ----
        #pragma unroll
        for (int s2 = 0; s2 < 2; ++s2) {
            bf16x8 pf = *(const bf16x8*)&Prow[s2 * 32 + quad * 8];  // A[m=col][k]
            #pragma unroll
            for (int ht = 0; ht < 16; ++ht) {
                bf16x8 vf = *(const bf16x8*)(vbase + (size_t)ht * 16 * S_ + kb + s2 * 32);
                O[ht] = __builtin_amdgcn_mfma_f32_16x16x32_bf16(pf, vf, O[ht], 0, 0, 0);
            }
        }
    }

    // ---- 4-way cross-wave merge through fp32 LDS accumulator ----
    if (lane < 16) { mbuf[wave][lane] = m; lbuf[wave][lane] = l; }
    __syncthreads();

    float mm = fmaxf(fmaxf(mbuf[0][col], mbuf[1][col]),
                     fmaxf(mbuf[2][col], mbuf[3][col]));
    float aw = __expf(m - mm);                    // this wave's rescale
    float awr[4];
    #pragma unroll
    for (int r = 0; r < 4; ++r) awr[r] = __shfl(aw, quad * 4 + r);

    #pragma unroll
    for (int w = 0; w < 4; ++w) {
        if (wave == w) {
            #pragma unroll
            for (int ht = 0; ht < 16; ++ht)
                #pragma unroll
                for (int r = 0; r < 4; ++r) {
                    float val = O[ht][r] * awr[r];
                    if (w != 0) val += Obuf[quad * 4 + r][ht * 16 + col];
                    Obuf[quad * 4 + r][ht * 16 + col] = val;
                }
        }
        __syncthreads();
    }

    // ---- LayerNorm over h (256), cooperative: q = tid>>4, i = tid&15 ----
    {
        const int q = tid >> 4;
        const int i = tid & 15;
        float mmq = fmaxf(fmaxf(mbuf[0][q], mbuf[1][q]),
                          fmaxf(mbuf[2][q], mbuf[3][q]));
        float ltq = lbuf[0][q] * __expf(mbuf[0][q] - mmq)
                  + lbuf[1][q] * __expf(mbuf[1][q] - mmq)
                  + lbuf[2][q] * __expf(mbuf[2][q] - mmq)
                  + lbuf[3][q] * __expf(mbuf[3][q] - mmq);
        float rl = 1.0f / ltq;

        float vals[16];
        float sum = 0.0f;
        #pragma unroll
        for (int j = 0; j < 16; ++j) {
            vals[j] = Obuf[q][j * 16 + i] * rl;
            sum += vals[j];
        }
        sum += __shfl_xor(sum, 1);
        sum += __shfl_xor(sum, 2);
        sum += __shfl_xor(sum, 4);
        sum += __shfl_xor(sum, 8);
        float mu = sum * (1.0f / H_);
        float sq = 0.0f;
        #pragma unroll
        for (int j = 0; j < 16; ++j) {
            float d = vals[j] - mu;
            sq += d * d;
        }
        sq += __shfl_xor(sq, 1);
        sq += __shfl_xor(sq, 2);
        sq += __shfl_xor(sq, 4);
        sq += __shfl_xor(sq, 8);
        float rstd = rsqrtf(sq * (1.0f / H_) + 1e-6f);

        float* orow = out + (size_t)(b * S_ + q0 + q) * H_;
        #pragma unroll
        for (int j = 0; j < 16; ++j) {
            int h = j * 16 + i;
            orow[h] = (vals[j] - mu) * rstd * gamma[h] + beta[h];
        }
    }
}

// ---------------------------------------------------------------------------
extern "C" void kernel_launch(void* const* d_in, const int* in_sizes, int n_in,
                              void* d_out, int out_size, void* d_ws, size_t ws_size,
                              hipStream_t stream)
{
    const float* query = (const float*)d_in[0];
    const float* key   = (const float*)d_in[1];
    const float* value = (const float*)d_in[2];
    const int*   mask  = (const int*)d_in[3];
    const float* Wq = (const float*)d_in[4];
    const float* bq = (const float*)d_in[5];
    const float* Wk = (const float*)d_in[6];
    const float* bk = (const float*)d_in[7];
    const float* Wv = (const float*)d_in[8];
    const float* bv = (const float*)d_in[9];
    const float* gamma = (const float*)d_in[10];
    const float* beta  = (const float*)d_in[11];
    float* out = (float*)d_out;

    unsigned short* qp = (unsigned short*)d_ws;          // [8][2048][256] bf16
    unsigned short* kp = qp + (size_t)B_ * S_ * H_;      // [8][2048][256] bf16
    unsigned short* vt = kp + (size_t)B_ * S_ * H_;      // [8][256][2048] bf16
    unsigned short* wt = vt + (size_t)B_ * S_ * H_;      // [3][256][96] bf16

    wconv_kernel<<<24, 256, 0, stream>>>(Wq, Wk, Wv, wt);
    proj_mfma_kernel<<<B_ * S_ / 16, 64, 0, stream>>>(query, key, value, wt,
                                                      bq, bk, bv, qp, kp, vt);
    attn_kernel<<<B_ * S_ / 16, 256, 0, stream>>>(qp, kp, vt, mask, gamma, beta, out);
}

// Round 3
// 492.754 us; speedup vs baseline: 1.0781x; 1.0781x over previous
//
#include <hip/hip_runtime.h>

#define B_   8
#define S_   2048
#define IN_  96
#define H_   256

typedef float f32x4 __attribute__((ext_vector_type(4)));
typedef short bf16x8 __attribute__((ext_vector_type(8)));   // 8 bf16 in 4 VGPRs

__device__ __forceinline__ unsigned short f2bf(float x) {
    unsigned int u = __float_as_uint(x);
    u += 0x7fffu + ((u >> 16) & 1u);          // round-nearest-even
    return (unsigned short)(u >> 16);
}

// ---------------------------------------------------------------------------
// Kernel 0: convert W[96][256] fp32 -> wt[256][96] bf16 (transposed), x3 proj.
// ---------------------------------------------------------------------------
__global__ __launch_bounds__(256) void wconv_kernel(
    const float* __restrict__ Wq, const float* __restrict__ Wk,
    const float* __restrict__ Wv, unsigned short* __restrict__ wt)
{
    const int p  = blockIdx.x >> 3;
    const int h0 = (blockIdx.x & 7) * 32;
    const float* W = (p == 0) ? Wq : (p == 1) ? Wk : Wv;
    unsigned short* dst = wt + (size_t)p * H_ * IN_ + (size_t)h0 * IN_;

    __shared__ unsigned short lds[32][100];   // [h_local][f], padded
    const int t = threadIdx.x;
    #pragma unroll
    for (int i = 0; i < 12; ++i) {            // 3072 elements of this chunk
        int idx = i * 256 + t;
        int f = idx >> 5;                     // 0..95
        int hl = idx & 31;
        lds[hl][f] = f2bf(W[f * H_ + h0 + hl]);
    }
    __syncthreads();
    #pragma unroll
    for (int j = 0; j < 6; ++j) {             // 1536 u32 = 3072 ushort, coalesced
        int e = (j * 256 + t) * 2;            // local element index (even)
        int hl = e / IN_, f = e % IN_;
        unsigned int pk = (unsigned int)lds[hl][f] |
                          ((unsigned int)lds[hl][f + 1] << 16);
        ((unsigned int*)dst)[j * 256 + t] = pk;
    }
}

// ---------------------------------------------------------------------------
// Kernel 1: QKV projection via MFMA.  out^T[h][r] = sum_f wt[h][f] * X[r][f].
// Grid = 1024 strips x 3 proj x 2 h-halves = 6144 one-wave blocks (24 waves/CU).
// C layout: lane(col,quad) holds out[r=col][h = ht*16 + quad*4 + reg].
//   qp[b][s][h], kp[b][s][h] bf16 row-major; vt[b][h][s] bf16 transposed.
// ---------------------------------------------------------------------------
__global__ __launch_bounds__(64) void proj_mfma_kernel(
    const float* __restrict__ query, const float* __restrict__ key,
    const float* __restrict__ value, const unsigned short* __restrict__ wt,
    const float* __restrict__ bq, const float* __restrict__ bk,
    const float* __restrict__ bv,
    unsigned short* __restrict__ qp, unsigned short* __restrict__ kp,
    unsigned short* __restrict__ vt)
{
    const int lane = threadIdx.x;
    const int col  = lane & 15;
    const int quad = lane >> 4;

    const int bi    = blockIdx.x;
    const int strip = bi / 6;                 // 0..1023, 16 rows each
    const int rem   = bi - strip * 6;
    const int p     = rem >> 1;               // 0=q, 1=k, 2=v
    const int hh    = rem & 1;                // h-half: ht in [hh*8, hh*8+8)
    const int b  = strip >> 7;
    const int s0 = (strip & 127) << 4;

    const float* X    = (p == 0) ? query : (p == 1) ? key : value;
    const float* bias = (p == 0) ? bq    : (p == 1) ? bk  : bv;

    // B-fragments: X[r=col][k], k = kc*32 + quad*8 + j  (fp32 -> bf16)
    const float* Xrow = X + (size_t)(strip * 16 + col) * IN_ + quad * 8;
    bf16x8 xf[3];
    #pragma unroll
    for (int kc = 0; kc < 3; ++kc) {
        f32x4 lo = *(const f32x4*)(Xrow + kc * 32);
        f32x4 hi = *(const f32x4*)(Xrow + kc * 32 + 4);
        bf16x8 v;
        #pragma unroll
        for (int j = 0; j < 4; ++j) v[j]     = (short)f2bf(lo[j]);
        #pragma unroll
        for (int j = 0; j < 4; ++j) v[4 + j] = (short)f2bf(hi[j]);
        xf[kc] = v;
    }
    const unsigned short* wbase = wt + (size_t)p * H_ * IN_;

    #pragma unroll
    for (int ht2 = 0; ht2 < 8; ++ht2) {
        const int ht = hh * 8 + ht2;
        f32x4 acc = (f32x4)(0.0f);
        #pragma unroll
        for (int kc = 0; kc < 3; ++kc) {
            bf16x8 wf = *(const bf16x8*)(wbase + (size_t)(ht * 16 + col) * IN_
                                         + kc * 32 + quad * 8);
            acc = __builtin_amdgcn_mfma_f32_16x16x32_bf16(wf, xf[kc], acc, 0, 0, 0);
        }
        f32x4 b4 = *(const f32x4*)(bias + ht * 16 + quad * 4);
        acc += b4;
        if (p < 2) {
            unsigned short* dstp = (p == 0) ? qp : kp;
            unsigned long long pk = 0;
            #pragma unroll
            for (int r = 0; r < 4; ++r)
                pk |= (unsigned long long)f2bf(acc[r]) << (16 * r);
            *(unsigned long long*)&dstp[(size_t)(strip * 16 + col) * H_
                                        + ht * 16 + quad * 4] = pk;
        } else {
            #pragma unroll
            for (int r = 0; r < 4; ++r)
                vt[(size_t)b * H_ * S_ + (size_t)(ht * 16 + quad * 4 + r) * S_
                   + s0 + col] = f2bf(acc[r]);
        }
    }
}

// ---------------------------------------------------------------------------
// Kernel 2: flash attention (online softmax) + LayerNorm, fused.
// Block = 256 thr = 4 waves, one 16-row Q strip; waves split keys 4-way.
// XCD swizzle: batch = blockIdx.x & 7 so each XCD's co-resident blocks share
// one batch (K+V = 2 MB fits the 4 MB per-XCD L2).
// launch_bounds(256,2): VGPR cap 256 — round 2's (256,4) clamped to 64 VGPRs
// and spilled the O accumulator (WRITE_SIZE 16->102 MB). Never again.
// ---------------------------------------------------------------------------
__global__ __launch_bounds__(256, 2) void attn_kernel(
    const unsigned short* __restrict__ qp, const unsigned short* __restrict__ kp,
    const unsigned short* __restrict__ vt, const int* __restrict__ mask,
    const float* __restrict__ gamma, const float* __restrict__ beta,
    float* __restrict__ out)
{
    __shared__ unsigned short P_lds[4][16][72];   // per-wave P transpose buffer
    __shared__ float mbuf[4][16], lbuf[4][16];
    __shared__ float Obuf[16][260];               // fp32 merge accumulator (pad 260)

    const int tid  = threadIdx.x;
    const int wave = tid >> 6;
    const int lane = tid & 63;
    const int col  = lane & 15;                   // q index within strip
    const int quad = lane >> 4;

    const int b  = blockIdx.x & 7;                // batch == XCD (dispatch i%8)
    const int q0 = (blockIdx.x >> 3) << 4;

    // Q B-fragments, kept in registers for the whole kernel.
    const unsigned short* qbase = qp + (size_t)(b * S_ + q0 + col) * H_ + quad * 8;
    bf16x8 qf[8];
    #pragma unroll
    for (int s = 0; s < 8; ++s) qf[s] = *(const bf16x8*)(qbase + s * 32);

    f32x4 O[16];
    #pragma unroll
    for (int ht = 0; ht < 16; ++ht) O[ht] = (f32x4)(0.0f);
    float m = -1e30f, l = 0.0f;

    const unsigned short* kbase = kp + (size_t)(b * S_ + col) * H_ + quad * 8;
    const unsigned short* vbase = vt + (size_t)(b * H_ + col) * S_ + quad * 8;
    const int* mbase = mask + (size_t)(b * S_ + q0 + col) * S_ + quad * 4;
    unsigned short* Prow = &P_lds[wave][col][0];

    for (int kb = wave * 64; kb < S_; kb += 256) {
        int4 msk[4];
        #pragma unroll
        for (int mt = 0; mt < 4; ++mt)
            msk[mt] = *(const int4*)(mbase + kb + mt * 16);

        // ---- S^T = K · Q^T  (row = key, col = q) ----
        f32x4 St[4];
        #pragma unroll
        for (int mt = 0; mt < 4; ++mt) St[mt] = (f32x4)(0.0f);
        #pragma unroll
        for (int s = 0; s < 8; ++s) {
            #pragma unroll
            for (int mt = 0; mt < 4; ++mt) {
                bf16x8 kf = *(const bf16x8*)(kbase + (size_t)(kb + mt * 16) * H_ + s * 32);
                St[mt] = __builtin_amdgcn_mfma_f32_16x16x32_bf16(kf, qf[s], St[mt], 0, 0, 0);
            }
        }

        // ---- scale + mask + online softmax (stats per lane, q = col) ----
        float sc[4][4];
        float mloc = -1e30f;
        #pragma unroll
        for (int mt = 0; mt < 4; ++mt) {
            int mv[4] = { msk[mt].x, msk[mt].y, msk[mt].z, msk[mt].w };
            #pragma unroll
            for (int r = 0; r < 4; ++r) {
                float x = St[mt][r] * 0.0625f;          // / sqrt(256)
                x = (mv[r] == 0) ? -1e10f : x;
                sc[mt][r] = x;
                mloc = fmaxf(mloc, x);
            }
        }
        mloc = fmaxf(mloc, __shfl_xor(mloc, 16));
        mloc = fmaxf(mloc, __shfl_xor(mloc, 32));
        float mnew  = fmaxf(m, mloc);
        float alpha = __expf(m - mnew);
        float ps = 0.0f;
        #pragma unroll
        for (int mt = 0; mt < 4; ++mt) {
            unsigned long long pk64 = 0;
            #pragma unroll
            for (int r = 0; r < 4; ++r) {
                float p = __expf(sc[mt][r] - mnew);
                ps += p;
                pk64 |= (unsigned long long)f2bf(p) << (16 * r);
            }
            *(unsigned long long*)&Prow[mt * 16 + quad * 4] = pk64;
        }
        ps += __shfl_xor(ps, 16);
        ps += __shfl_xor(ps, 32);
        l = l * alpha + ps;
        m = mnew;

        float a4[4];
        #pragma unroll
        for (int r = 0; r < 4; ++r) a4[r] = __shfl(alpha, quad * 4 + r);
        #pragma unroll
        for (int ht = 0; ht < 16; ++ht) {
            O[ht][0] *= a4[0]; O[ht][1] *= a4[1];
            O[ht][2] *= a4[2]; O[ht][3] *= a4[3];
        }

        // ---- O += P · V ----
        #pragma unroll
        for (int s2 = 0; s2 < 2; ++s2) {
            bf16x8 pf = *(const bf16x8*)&Prow[s2 * 32 + quad * 8];  // A[m=col][k]
            #pragma unroll
            for (int ht = 0; ht < 16; ++ht) {
                bf16x8 vf = *(const bf16x8*)(vbase + (size_t)ht * 16 * S_ + kb + s2 * 32);
                O[ht] = __builtin_amdgcn_mfma_f32_16x16x32_bf16(pf, vf, O[ht], 0, 0, 0);
            }
        }
    }

    // ---- 4-way cross-wave merge through fp32 LDS accumulator ----
    if (lane < 16) { mbuf[wave][lane] = m; lbuf[wave][lane] = l; }
    __syncthreads();

    float mm = fmaxf(fmaxf(mbuf[0][col], mbuf[1][col]),
                     fmaxf(mbuf[2][col], mbuf[3][col]));
    float aw = __expf(m - mm);                    // this wave's rescale
    float awr[4];
    #pragma unroll
    for (int r = 0; r < 4; ++r) awr[r] = __shfl(aw, quad * 4 + r);

    #pragma unroll
    for (int w = 0; w < 4; ++w) {
        if (wave == w) {
            #pragma unroll
            for (int ht = 0; ht < 16; ++ht)
                #pragma unroll
                for (int r = 0; r < 4; ++r) {
                    float val = O[ht][r] * awr[r];
                    if (w != 0) val += Obuf[quad * 4 + r][ht * 16 + col];
                    Obuf[quad * 4 + r][ht * 16 + col] = val;
                }
        }
        __syncthreads();
    }

    // ---- LayerNorm over h (256), cooperative: q = tid>>4, i = tid&15 ----
    {
        const int q = tid >> 4;
        const int i = tid & 15;
        float mmq = fmaxf(fmaxf(mbuf[0][q], mbuf[1][q]),
                          fmaxf(mbuf[2][q], mbuf[3][q]));
        float ltq = lbuf[0][q] * __expf(mbuf[0][q] - mmq)
                  + lbuf[1][q] * __expf(mbuf[1][q] - mmq)
                  + lbuf[2][q] * __expf(mbuf[2][q] - mmq)
                  + lbuf[3][q] * __expf(mbuf[3][q] - mmq);
        float rl = 1.0f / ltq;

        float vals[16];
        float sum = 0.0f;
        #pragma unroll
        for (int j = 0; j < 16; ++j) {
            vals[j] = Obuf[q][j * 16 + i] * rl;
            sum += vals[j];
        }
        sum += __shfl_xor(sum, 1);
        sum += __shfl_xor(sum, 2);
        sum += __shfl_xor(sum, 4);
        sum += __shfl_xor(sum, 8);
        float mu = sum * (1.0f / H_);
        float sq = 0.0f;
        #pragma unroll
        for (int j = 0; j < 16; ++j) {
            float d = vals[j] - mu;
            sq += d * d;
        }
        sq += __shfl_xor(sq, 1);
        sq += __shfl_xor(sq, 2);
        sq += __shfl_xor(sq, 4);
        sq += __shfl_xor(sq, 8);
        float rstd = rsqrtf(sq * (1.0f / H_) + 1e-6f);

        float* orow = out + (size_t)(b * S_ + q0 + q) * H_;
        #pragma unroll
        for (int j = 0; j < 16; ++j) {
            int h = j * 16 + i;
            orow[h] = (vals[j] - mu) * rstd * gamma[h] + beta[h];
        }
    }
}

// ---------------------------------------------------------------------------
extern "C" void kernel_launch(void* const* d_in, const int* in_sizes, int n_in,
                              void* d_out, int out_size, void* d_ws, size_t ws_size,
                              hipStream_t stream)
{
    const float* query = (const float*)d_in[0];
    const float* key   = (const float*)d_in[1];
    const float* value = (const float*)d_in[2];
    const int*   mask  = (const int*)d_in[3];
    const float* Wq = (const float*)d_in[4];
    const float* bq = (const float*)d_in[5];
    const float* Wk = (const float*)d_in[6];
    const float* bk = (const float*)d_in[7];
    const float* Wv = (const float*)d_in[8];
    const float* bv = (const float*)d_in[9];
    const float* gamma = (const float*)d_in[10];
    const float* beta  = (const float*)d_in[11];
    float* out = (float*)d_out;

    unsigned short* qp = (unsigned short*)d_ws;          // [8][2048][256] bf16
    unsigned short* kp = qp + (size_t)B_ * S_ * H_;      // [8][2048][256] bf16
    unsigned short* vt = kp + (size_t)B_ * S_ * H_;      // [8][256][2048] bf16
    unsigned short* wt = vt + (size_t)B_ * S_ * H_;      // [3][256][96] bf16

    wconv_kernel<<<24, 256, 0, stream>>>(Wq, Wk, Wv, wt);
    proj_mfma_kernel<<<B_ * S_ / 16 * 6, 64, 0, stream>>>(query, key, value, wt,
                                                          bq, bk, bv, qp, kp, vt);
    attn_kernel<<<B_ * S_ / 16, 256, 0, stream>>>(qp, kp, vt, mask, gamma, beta, out);
}

// Round 4
// 465.752 us; speedup vs baseline: 1.1406x; 1.0580x over previous
//
#include <hip/hip_runtime.h>

#define B_   8
#define S_   2048
#define IN_  96
#define H_   256

typedef float f32x4 __attribute__((ext_vector_type(4)));
typedef short bf16x8 __attribute__((ext_vector_type(8)));   // 8 bf16 in 4 VGPRs

__device__ __forceinline__ unsigned short f2bf(float x) {
    unsigned int u = __float_as_uint(x);
    u += 0x7fffu + ((u >> 16) & 1u);          // round-nearest-even
    return (unsigned short)(u >> 16);
}

// ---------------------------------------------------------------------------
// Kernel 0: convert W[96][256] fp32 -> wt[256][96] bf16 (transposed), x3 proj.
// ---------------------------------------------------------------------------
__global__ __launch_bounds__(256) void wconv_kernel(
    const float* __restrict__ Wq, const float* __restrict__ Wk,
    const float* __restrict__ Wv, unsigned short* __restrict__ wt)
{
    const int p  = blockIdx.x >> 3;
    const int h0 = (blockIdx.x & 7) * 32;
    const float* W = (p == 0) ? Wq : (p == 1) ? Wk : Wv;
    unsigned short* dst = wt + (size_t)p * H_ * IN_ + (size_t)h0 * IN_;

    __shared__ unsigned short lds[32][100];   // [h_local][f], padded
    const int t = threadIdx.x;
    #pragma unroll
    for (int i = 0; i < 12; ++i) {
        int idx = i * 256 + t;
        int f = idx >> 5;                     // 0..95
        int hl = idx & 31;
        lds[hl][f] = f2bf(W[f * H_ + h0 + hl]);
    }
    __syncthreads();
    #pragma unroll
    for (int j = 0; j < 6; ++j) {
        int e = (j * 256 + t) * 2;
        int hl = e / IN_, f = e % IN_;
        unsigned int pk = (unsigned int)lds[hl][f] |
                          ((unsigned int)lds[hl][f + 1] << 16);
        ((unsigned int*)dst)[j * 256 + t] = pk;
    }
}

// ---------------------------------------------------------------------------
// Kernel 1: QKV projection via MFMA, v2.
// 1024 blocks x 256 thr (4 waves, 16 waves/CU). Block = one 16-row strip, all
// 3 projections; wave w owns h-chunk [w*64, w*64+64).
// q/k use C[r][h] = mfma(A=X, B=W^T-row) -> stores are 32-B h-runs.
// v   uses C[h][r] = mfma(A=W^T-row, B=X) -> transposed stores are 32-B s-runs.
// Same fragment registers, just swapped operand order.
// ---------------------------------------------------------------------------
__global__ __launch_bounds__(256) void proj_kernel2(
    const float* __restrict__ query, const float* __restrict__ key,
    const float* __restrict__ value, const unsigned short* __restrict__ wt,
    const float* __restrict__ bq, const float* __restrict__ bk,
    const float* __restrict__ bv,
    unsigned short* __restrict__ qp, unsigned short* __restrict__ kp,
    unsigned short* __restrict__ vt)
{
    __shared__ unsigned short Xs[3][16][104];     // [p][r][f], pitch 104 (16B-align)

    const int t    = threadIdx.x;
    const int lane = t & 63;
    const int wave = t >> 6;
    const int col  = lane & 15;
    const int quad = lane >> 4;
    const int s0   = blockIdx.x * 16;             // flat row (b*S + sl)
    const int b    = s0 >> 11;
    const int sl   = s0 & (S_ - 1);

    const float* srcs[3] = { query + (size_t)s0 * IN_,
                             key   + (size_t)s0 * IN_,
                             value + (size_t)s0 * IN_ };
    #pragma unroll
    for (int p = 0; p < 3; ++p) {
        #pragma unroll
        for (int i = 0; i < 2; ++i) {
            int idx = i * 256 + t;                // float4 index, 384 total
            if (idx < 384) {
                f32x4 x = *(const f32x4*)(srcs[p] + idx * 4);
                int r = idx / 24;                 // 24 float4 per 96-f row
                int f = (idx - r * 24) * 4;
                unsigned long long pk =
                    (unsigned long long)f2bf(x[0])
                  | ((unsigned long long)f2bf(x[1]) << 16)
                  | ((unsigned long long)f2bf(x[2]) << 32)
                  | ((unsigned long long)f2bf(x[3]) << 48);
                *(unsigned long long*)&Xs[p][r][f] = pk;
            }
        }
    }
    __syncthreads();

    const int hc = wave;                          // 64-h chunk
    #pragma unroll
    for (int p = 0; p < 3; ++p) {
        const unsigned short* wbase = wt + (size_t)p * H_ * IN_;
        bf16x8 wfr[4][3];
        #pragma unroll
        for (int ht = 0; ht < 4; ++ht)
            #pragma unroll
            for (int kc = 0; kc < 3; ++kc)
                wfr[ht][kc] = *(const bf16x8*)(wbase
                    + (size_t)(hc * 64 + ht * 16 + col) * IN_ + kc * 32 + quad * 8);
        bf16x8 xfr[3];
        #pragma unroll
        for (int kc = 0; kc < 3; ++kc)
            xfr[kc] = *(const bf16x8*)&Xs[p][col][kc * 32 + quad * 8];

        f32x4 acc[4];
        #pragma unroll
        for (int ht = 0; ht < 4; ++ht) acc[ht] = (f32x4)(0.0f);
        #pragma unroll
        for (int kc = 0; kc < 3; ++kc)
            #pragma unroll
            for (int ht = 0; ht < 4; ++ht)
                acc[ht] = (p < 2)
                    ? __builtin_amdgcn_mfma_f32_16x16x32_bf16(xfr[kc], wfr[ht][kc], acc[ht], 0, 0, 0)
                    : __builtin_amdgcn_mfma_f32_16x16x32_bf16(wfr[ht][kc], xfr[kc], acc[ht], 0, 0, 0);

        if (p < 2) {
            unsigned short* dst  = (p == 0) ? qp : kp;
            const float*    bias = (p == 0) ? bq : bk;
            #pragma unroll
            for (int ht = 0; ht < 4; ++ht) {
                float bh = bias[hc * 64 + ht * 16 + col];
                #pragma unroll
                for (int r = 0; r < 4; ++r)
                    dst[(size_t)(s0 + quad * 4 + r) * H_ + hc * 64 + ht * 16 + col]
                        = f2bf(acc[ht][r] + bh);
            }
        } else {
            #pragma unroll
            for (int ht = 0; ht < 4; ++ht) {
                f32x4 b4 = *(const f32x4*)(bv + hc * 64 + ht * 16 + quad * 4);
                #pragma unroll
                for (int r = 0; r < 4; ++r)
                    vt[(size_t)(b * H_ + hc * 64 + ht * 16 + quad * 4 + r) * S_
                       + sl + col] = f2bf(acc[ht][r] + b4[r]);
            }
        }
    }
}

// ---------------------------------------------------------------------------
// Kernel 2: flash attention + LayerNorm, cooperative-chunk version.
// Block = 256 thr = 4 waves, 16-row Q strip. Per 256-key chunk: wave w QK^Ts
// keys [w*64, w*64+64), chunk-wide softmax stats merged via LDS, P (bf16)
// shared in LDS; each wave then PVs its own 64-h slice (O = 16 regs, not 64).
// Register budget fits __launch_bounds__(256,4) -> 16 waves/CU, no spill.
// ---------------------------------------------------------------------------
__global__ __launch_bounds__(256, 4) void attn_kernel(
    const unsigned short* __restrict__ qp, const unsigned short* __restrict__ kp,
    const unsigned short* __restrict__ vt, const int* __restrict__ mask,
    const float* __restrict__ gamma, const float* __restrict__ beta,
    float* __restrict__ out)
{
    __shared__ union {
        unsigned short P[2][16][264];             // [buf][q][k_local], pitch 264
        float Obuf[16][260];                      // [q][h] final merge (aliased)
    } sm;
    __shared__ float wmax[2][4][16], wsum[2][4][16];

    const int tid  = threadIdx.x;
    const int wave = tid >> 6;
    const int lane = tid & 63;
    const int col  = lane & 15;
    const int quad = lane >> 4;

    const int b  = blockIdx.x & 7;                // batch == XCD (L2 locality)
    const int q0 = (blockIdx.x >> 3) << 4;

    // Q B-fragments (col = q row), resident all kernel: 32 VGPRs.
    const unsigned short* qbase = qp + (size_t)(b * S_ + q0 + col) * H_ + quad * 8;
    bf16x8 qf[8];
    #pragma unroll
    for (int s = 0; s < 8; ++s) qf[s] = *(const bf16x8*)(qbase + s * 32);

    f32x4 O[4];                                   // 64-h slice: 16 regs
    #pragma unroll
    for (int ht = 0; ht < 4; ++ht) O[ht] = (f32x4)(0.0f);
    float m = -1e30f, l = 0.0f;

    const unsigned short* kbase = kp + (size_t)(b * S_ + col) * H_ + quad * 8;
    const unsigned short* vbase = vt + (size_t)(b * H_ + wave * 64 + col) * S_ + quad * 8;
    const int* mbase = mask + (size_t)(b * S_ + q0 + col) * S_ + quad * 4;

    for (int c = 0; c < 8; ++c) {
        const int kb = c * 256;
        const int k0 = kb + wave * 64;            // this wave's QK^T subtile
        const int pb = c & 1;

        // ---- S^T for 64 keys: row=key, col=q.  mt-outer frees mask early. ----
        f32x4 St[4];
        float mloc = -1e30f;
        #pragma unroll
        for (int mt = 0; mt < 4; ++mt) {
            int4 mv = *(const int4*)(mbase + k0 + mt * 16);
            f32x4 st = (f32x4)(0.0f);
            #pragma unroll
            for (int s = 0; s < 8; ++s) {
                bf16x8 kf = *(const bf16x8*)(kbase + (size_t)(k0 + mt * 16) * H_ + s * 32);
                st = __builtin_amdgcn_mfma_f32_16x16x32_bf16(kf, qf[s], st, 0, 0, 0);
            }
            int mi[4] = { mv.x, mv.y, mv.z, mv.w };
            #pragma unroll
            for (int r = 0; r < 4; ++r) {
                float x = (mi[r] == 0) ? -1e10f : st[r] * 0.0625f;  // /sqrt(256)
                St[mt][r] = x;
                mloc = fmaxf(mloc, x);
            }
        }
        mloc = fmaxf(mloc, __shfl_xor(mloc, 16));
        mloc = fmaxf(mloc, __shfl_xor(mloc, 32));
        if (lane < 16) wmax[pb][wave][lane] = mloc;
        __syncthreads();                          // barrier A: stats visible

        float cmax = fmaxf(fmaxf(wmax[pb][0][col], wmax[pb][1][col]),
                           fmaxf(wmax[pb][2][col], wmax[pb][3][col]));
        float mnew  = fmaxf(m, cmax);
        float alpha = __expf(m - mnew);
        float ps = 0.0f;
        #pragma unroll
        for (int mt = 0; mt < 4; ++mt) {
            unsigned long long pk64 = 0;
            #pragma unroll
            for (int r = 0; r < 4; ++r) {
                float p = __expf(St[mt][r] - mnew);
                ps += p;
                pk64 |= (unsigned long long)f2bf(p) << (16 * r);
            }
            *(unsigned long long*)&sm.P[pb][col][wave * 64 + mt * 16 + quad * 4] = pk64;
        }
        ps += __shfl_xor(ps, 16);
        ps += __shfl_xor(ps, 32);
        if (lane < 16) wsum[pb][wave][lane] = ps;
        __syncthreads();                          // barrier B: P + sums visible

        l = l * alpha + (wsum[pb][0][col] + wsum[pb][1][col]
                       + wsum[pb][2][col] + wsum[pb][3][col]);
        m = mnew;

        // rescale O rows (q = quad*4+r) by alpha of that q
        float a4[4];
        #pragma unroll
        for (int r = 0; r < 4; ++r) a4[r] = __shfl(alpha, quad * 4 + r);
        #pragma unroll
        for (int ht = 0; ht < 4; ++ht) {
            O[ht][0] *= a4[0]; O[ht][1] *= a4[1];
            O[ht][2] *= a4[2]; O[ht][3] *= a4[3];
        }

        // ---- PV over full 256-key chunk, this wave's 64-h slice ----
        #pragma unroll
        for (int s2 = 0; s2 < 8; ++s2) {
            bf16x8 pf = *(const bf16x8*)&sm.P[pb][col][s2 * 32 + quad * 8];
            #pragma unroll
            for (int ht = 0; ht < 4; ++ht) {
                bf16x8 vf = *(const bf16x8*)(vbase + (size_t)ht * 16 * S_ + kb + s2 * 32);
                O[ht] = __builtin_amdgcn_mfma_f32_16x16x32_bf16(pf, vf, O[ht], 0, 0, 0);
            }
        }
    }

    // ---- epilogue: normalize by l, gather all h in LDS (aliases P!), LN ----
    float linv = 1.0f / l;                        // per-lane, q = col
    float li4[4];
    #pragma unroll
    for (int r = 0; r < 4; ++r) li4[r] = __shfl(linv, quad * 4 + r);
    __syncthreads();                              // P reads done before alias
    #pragma unroll
    for (int ht = 0; ht < 4; ++ht)
        #pragma unroll
        for (int r = 0; r < 4; ++r)
            sm.Obuf[quad * 4 + r][wave * 64 + ht * 16 + col] = O[ht][r] * li4[r];
    __syncthreads();

    {
        const int q = tid >> 4;
        const int i = tid & 15;
        float vals[16];
        float sum = 0.0f;
        #pragma unroll
        for (int j = 0; j < 16; ++j) {
            vals[j] = sm.Obuf[q][j * 16 + i];
            sum += vals[j];
        }
        sum += __shfl_xor(sum, 1);
        sum += __shfl_xor(sum, 2);
        sum += __shfl_xor(sum, 4);
        sum += __shfl_xor(sum, 8);
        float mu = sum * (1.0f / H_);
        float sq = 0.0f;
        #pragma unroll
        for (int j = 0; j < 16; ++j) {
            float d = vals[j] - mu;
            sq += d * d;
        }
        sq += __shfl_xor(sq, 1);
        sq += __shfl_xor(sq, 2);
        sq += __shfl_xor(sq, 4);
        sq += __shfl_xor(sq, 8);
        float rstd = rsqrtf(sq * (1.0f / H_) + 1e-6f);

        float* orow = out + (size_t)(b * S_ + q0 + q) * H_;
        #pragma unroll
        for (int j = 0; j < 16; ++j) {
            int h = j * 16 + i;
            orow[h] = (vals[j] - mu) * rstd * gamma[h] + beta[h];
        }
    }
}

// ---------------------------------------------------------------------------
extern "C" void kernel_launch(void* const* d_in, const int* in_sizes, int n_in,
                              void* d_out, int out_size, void* d_ws, size_t ws_size,
                              hipStream_t stream)
{
    const float* query = (const float*)d_in[0];
    const float* key   = (const float*)d_in[1];
    const float* value = (const float*)d_in[2];
    const int*   mask  = (const int*)d_in[3];
    const float* Wq = (const float*)d_in[4];
    const float* bq = (const float*)d_in[5];
    const float* Wk = (const float*)d_in[6];
    const float* bk = (const float*)d_in[7];
    const float* Wv = (const float*)d_in[8];
    const float* bv = (const float*)d_in[9];
    const float* gamma = (const float*)d_in[10];
    const float* beta  = (const float*)d_in[11];
    float* out = (float*)d_out;

    unsigned short* qp = (unsigned short*)d_ws;          // [8][2048][256] bf16
    unsigned short* kp = qp + (size_t)B_ * S_ * H_;      // [8][2048][256] bf16
    unsigned short* vt = kp + (size_t)B_ * S_ * H_;      // [8][256][2048] bf16
    unsigned short* wt = vt + (size_t)B_ * S_ * H_;      // [3][256][96] bf16

    wconv_kernel<<<24, 256, 0, stream>>>(Wq, Wk, Wv, wt);
    proj_kernel2<<<B_ * S_ / 16, 256, 0, stream>>>(query, key, value, wt,
                                                   bq, bk, bv, qp, kp, vt);
    attn_kernel<<<B_ * S_ / 16, 256, 0, stream>>>(qp, kp, vt, mask, gamma, beta, out);
}